// Round 13
// baseline (265.946 us; speedup 1.0000x reference)
//
#include <hip/hip_runtime.h>

// Problem constants (fixed by setup_inputs):
//   a_arc, s_arc : [64, 1024, 1024] f32
//   adds, pos    : [64, 1024] int32 in [0, 50)
constexpr int NPOS  = 50;
constexpr int NBINS = NPOS * NPOS;   // 2500
constexpr int SL    = 1024;
constexpr int BZ    = 64;
constexpr float ALPHA = 0.3f;

// ---------------- hist (register-array) config ----------------
constexpr int H_THREADS = 256;                 // thread owns ONE column
constexpr int COLCH     = 4;                   // 4 x 256 cols
constexpr int ROWSP     = 4;                   // 4 x 256 rows
constexpr int H_ROWS    = SL / ROWSP;          // 256
constexpr int H_BLOCKS  = BZ * COLCH * ROWSP;  // 1024
constexpr int PS        = 2512;                // slice stride (floats, 16B-mult)

// ---------------- reduce2 / apply config ----------------
constexpr int R2_BLOCKS = 40;                  // 64 bins per block
constexpr int A_THREADS      = 256;
constexpr int ROWS_PER_BLOCK = 32;
constexpr int BLOCKS_PER_B   = SL / ROWS_PER_BLOCK;   // 32
constexpr int A_BLOCKS       = BZ * BLOCKS_PER_B;     // 2048

// ---------------------------------------------------------------------------
// Kernel 1: per-(b, colchunk, rowsplit) partials with REGISTER-ARRAY
// accumulation. p = adds[row] is wave-uniform (threads own columns), so
// acc[p] += v compiles to a scalar jump table + one v_add — zero LDS ops,
// zero atomics, zero RMW chains in the main loop, natural-order coalesced
// 256-B streaming with 8 loads in flight. acc[] indices are compile-time
// constants in every case -> stays in VGPRs (rule #20).
// ---------------------------------------------------------------------------
__global__ __launch_bounds__(H_THREADS) void hist_reg(
    const float* __restrict__ a, const int* __restrict__ adds,
    float* __restrict__ g_part) {
  __shared__ float accL[NPOS][H_THREADS];   // 50 KB, written once at dump
  __shared__ int   order2[H_THREADS];       // this block's cols sorted by q
  __shared__ int   cntQ[NPOS], offQs[NPOS], offQm[NPOS];

  const int tid = threadIdx.x;
  const int b   = blockIdx.x / (COLCH * ROWSP);
  const int rem = blockIdx.x % (COLCH * ROWSP);
  const int cc  = rem / ROWSP;
  const int rs  = rem % ROWSP;
  const int col = cc * H_THREADS + tid;
  const int r0  = rs * H_ROWS;

  // --- col-sort setup (verified counting-sort pattern, 256 elems) ---
  const int q = adds[(size_t)b * SL + col];   // this thread's column bin
  if (tid < NPOS) cntQ[tid] = 0;
  __syncthreads();
  atomicAdd(&cntQ[q], 1);
  __syncthreads();
  if (tid == 0) {
    int run = 0;
    for (int c = 0; c < NPOS; ++c) { offQs[c] = run; offQm[c] = run; run += cntQ[c]; }
  }
  __syncthreads();
  order2[atomicAdd(&offQm[q], 1)] = tid;
  __syncthreads();

  // --- main loop: 256 rows, 8 loads in flight, uniform-switch accumulate ---
  float acc[NPOS];
  #pragma unroll
  for (int p = 0; p < NPOS; ++p) acc[p] = 0.0f;

  const float* __restrict__ Ar = a + ((size_t)b * SL + r0) * SL + col;
  const int*   __restrict__ Pr = adds + (size_t)b * SL + r0;

#define C1(P)  case (P): acc[(P)] += x; break;
#define C10(P) C1(P) C1((P)+1) C1((P)+2) C1((P)+3) C1((P)+4) \
               C1((P)+5) C1((P)+6) C1((P)+7) C1((P)+8) C1((P)+9)
  auto addp = [&](int p, float x) {
    switch (p) { C10(0) C10(10) C10(20) C10(30) C10(40) default: break; }
  };
#undef C10
#undef C1

  for (int r = 0; r < H_ROWS; r += 8) {
    float v[8];
    #pragma unroll
    for (int u = 0; u < 8; ++u)               // 8 independent 256-B loads
      v[u] = Ar[(size_t)(r + u) * SL];
    const int4 p0 = *(const int4*)(Pr + r);   // uniform addr -> scalar loads
    const int4 p1 = *(const int4*)(Pr + r + 4);
    const int pp[8] = {p0.x, p0.y, p0.z, p0.w, p1.x, p1.y, p1.z, p1.w};
    #pragma unroll
    for (int u = 0; u < 8; ++u)
      addp(__builtin_amdgcn_readfirstlane(pp[u]), v[u]);  // scalar jump table
  }

  // --- dump registers to LDS (conflict-free), then q-sorted col-reduce ---
  #pragma unroll
  for (int p = 0; p < NPOS; ++p) accL[p][tid] = acc[p];
  __syncthreads();

  float* __restrict__ gp = g_part + (size_t)blockIdx.x * PS;
  for (int bin = tid; bin < NBINS; bin += H_THREADS) {
    const int p = bin / NPOS, qq = bin % NPOS;
    const int s0 = offQs[qq], n = cntQ[qq];
    float s = 0.0f;
    for (int k = 0; k < n; ++k) s += accL[p][order2[s0 + k]];
    gp[bin] = s;                              // plain store, private slice
  }
}

// ---------------------------------------------------------------------------
// Kernel 1.5: g_hist[bin] = sum over 1024 slices. Block = 64 bins x 4
// slice-quarters; plain stores, no atomics, no memset.
// ---------------------------------------------------------------------------
__global__ __launch_bounds__(256) void reduce2(
    const float* __restrict__ g_part, float* __restrict__ g_hist) {
  __shared__ float red[4][64];
  const int l = threadIdx.x & 63, w = threadIdx.x >> 6;
  const int bin = blockIdx.x * 64 + l;
  float s = 0.0f;
  if (bin < NBINS) {
    const float* __restrict__ base = g_part + (size_t)(w * 256) * PS + bin;
    #pragma unroll 8
    for (int r = 0; r < 256; ++r) s += base[(size_t)r * PS];
  }
  red[w][l] = s;
  __syncthreads();
  if (w == 0 && bin < NBINS)
    g_hist[bin] = red[0][l] + red[1][l] + red[2][l] + red[3][l];
}

// ---------------------------------------------------------------------------
// Kernel 2: out = s_arc + ALPHA * sigmoid(g_hist)[pos-pair bin]
// Measured ~6.1 TB/s (HBM roofline) — unchanged.
// ---------------------------------------------------------------------------
__global__ __launch_bounds__(A_THREADS) void apply_kernel(
    const float* __restrict__ s, const int* __restrict__ pos,
    const float* __restrict__ g_hist, float* __restrict__ out) {
  __shared__ float sig[NBINS];
  __shared__ int   pos_s[SL];

  const int tid = threadIdx.x;
  const int b   = blockIdx.x / BLOCKS_PER_B;
  const int i0  = (blockIdx.x % BLOCKS_PER_B) * ROWS_PER_BLOCK;

  ((int4*)pos_s)[tid] = ((const int4*)(pos + (size_t)b * SL))[tid];
  for (int k = tid; k < NBINS; k += A_THREADS) {
    const float h = g_hist[k];
    sig[k] = 1.0f / (1.0f + __expf(-h));
  }
  __syncthreads();

  const int4 pj = ((const int4*)pos_s)[tid];
  const size_t rowoff = ((size_t)b * SL + i0) * SL;
  const float4* __restrict__ srow = (const float4*)(s + rowoff);
  float4* __restrict__ orow = (float4*)(out + rowoff);

  for (int r = 0; r < ROWS_PER_BLOCK; ++r) {
    const int base = pos_s[i0 + r] * NPOS;    // wave-uniform broadcast
    const float4 sv = srow[(size_t)r * (SL / 4) + tid];
    float4 ov;
    ov.x = sv.x + ALPHA * sig[base + pj.x];
    ov.y = sv.y + ALPHA * sig[base + pj.y];
    ov.z = sv.z + ALPHA * sig[base + pj.z];
    ov.w = sv.w + ALPHA * sig[base + pj.w];
    orow[(size_t)r * (SL / 4) + tid] = ov;
  }
}

extern "C" void kernel_launch(void* const* d_in, const int* in_sizes, int n_in,
                              void* d_out, int out_size, void* d_ws, size_t ws_size,
                              hipStream_t stream) {
  const float* a_arc = (const float*)d_in[0];
  const float* s_arc = (const float*)d_in[1];
  const int*   adds  = (const int*)d_in[2];
  const int*   pos   = (const int*)d_in[3];
  float* out    = (float*)d_out;
  float* g_hist = (float*)d_ws;                 // 2500 floats
  float* g_part = g_hist + 4096;                // 1024 x 2512 floats = 10.3 MB

  // No memset needed: all outputs are fully overwritten with plain stores
  // every call (no atomic accumulation anywhere).
  hist_reg    <<<H_BLOCKS, H_THREADS, 0, stream>>>(a_arc, adds, g_part);
  reduce2     <<<R2_BLOCKS, 256, 0, stream>>>(g_part, g_hist);
  apply_kernel<<<A_BLOCKS, A_THREADS, 0, stream>>>(s_arc, pos, g_hist, out);
}

// Round 14
// 199.515 us; speedup vs baseline: 1.3330x; 1.3330x over previous
//
#include <hip/hip_runtime.h>

// Problem constants (fixed by setup_inputs):
//   a_arc, s_arc : [64, 1024, 1024] f32
//   adds, pos    : [64, 1024] int32 in [0, 50)
constexpr int NPOS  = 50;
constexpr int NBINS = NPOS * NPOS;   // 2500
constexpr int SL    = 1024;
constexpr int BZ    = 64;
constexpr float ALPHA = 0.3f;

// ---------------- hist (high-occupancy row-gather) config ----------------
constexpr int NRNG      = 13;                  // p-ranges of 4 (covers 0..49)
constexpr int NSPL      = 3;                   // row splits
constexpr int PSLICE    = 208;                 // slice stride (floats)
constexpr int H_THREADS = 256;                 // thread owns cols 4t..4t+3
constexpr int H_BLOCKS  = BZ * NRNG * NSPL;    // 2496  (~7 blocks/CU by LDS)
constexpr int LISTCAP   = 352;                 // max rows/split = 342

// ---------------- reduce2 / apply config ----------------
constexpr int R2_BLOCKS = (NBINS + 255) / 256; // 10
constexpr int A_THREADS      = 256;
constexpr int ROWS_PER_BLOCK = 32;
constexpr int BLOCKS_PER_B   = SL / ROWS_PER_BLOCK;   // 32
constexpr int A_BLOCKS       = BZ * BLOCKS_PER_B;     // 2048

// ---------------------------------------------------------------------------
// Kernel 1: per-(b, p-range of 4, row-third) partials. R10's verified main
// loop (sorted row list, readfirstlane tags, 8-deep ping-pong, 1-KB/wave-
// instr full-row loads, register run-accumulate, one plain LDS store per
// p-run) with the LDS footprint cut 45->22 KB: accL is [4][1024] and the
// col-sort machinery is replaced by a ONE-TIME 16-instr LDS-atomic col
// flush. Grid 512->2496 => ~7 blocks/CU (20-28 waves/CU) vs R10's 2.
// ---------------------------------------------------------------------------
__global__ __launch_bounds__(H_THREADS) void hist_gather(
    const float* __restrict__ a, const int* __restrict__ adds,
    float* __restrict__ g_part) {
  __shared__ float accL[4][SL];         // 16 KB: [pl][col], col = 4t..4t+3
  __shared__ float sbin[4 * NPOS];      // 800 B: [pl][q] partial bins
  __shared__ int   adds_s[SL];          // 4 KB
  __shared__ int   list[LISTCAP];       // 1.4 KB: (pl<<12)|row, sorted by pl
  __shared__ int   cnt4[4], offm[4];
  __shared__ int   nrows_s;

  const int tid = threadIdx.x;
  const int b   = blockIdx.x / (NRNG * NSPL);
  const int rem = blockIdx.x % (NRNG * NSPL);
  const int rg  = rem / NSPL;
  const int sp  = rem % NSPL;
  const int lo  = rg * 4;
  const int sz  = (NPOS - lo < 4) ? (NPOS - lo) : 4;   // 4; last range 2
  const int rlo = (sp * SL) / NSPL, rhi = ((sp + 1) * SL) / NSPL;

  ((int4*)adds_s)[tid] = ((const int4*)(adds + (size_t)b * SL))[tid];
  {
    const float4 z{0, 0, 0, 0};
    #pragma unroll
    for (int pl = 0; pl < 4; ++pl) ((float4*)&accL[pl][0])[tid] = z;
  }
  if (tid < 4) cnt4[tid] = 0;
  if (tid < 4 * NPOS) sbin[tid] = 0.0f;
  __syncthreads();

  // --- tiny counting sort: this third's rows with p in range, by pl ---
  for (int i = rlo + tid; i < rhi; i += H_THREADS) {
    const int pl = adds_s[i] - lo;
    if ((unsigned)pl < (unsigned)sz) atomicAdd(&cnt4[pl], 1);
  }
  __syncthreads();
  if (tid == 0) {
    int run = 0;
    #pragma unroll
    for (int c = 0; c < 4; ++c) { offm[c] = run; run += cnt4[c]; }
    nrows_s = run;
  }
  __syncthreads();
  for (int i = rlo + tid; i < rhi; i += H_THREADS) {
    const int pl = adds_s[i] - lo;
    if ((unsigned)pl < (unsigned)sz)
      list[atomicAdd(&offm[pl], 1)] = (pl << 12) | i;
  }
  __syncthreads();
  const int N = nrows_s, Npad = (N + 7) & ~7;
  if (tid < 8 && N + tid < Npad)        // sentinel pl=7 (flush-guarded)
    list[N + tid] = (7 << 12) | (list[N - 1] & 0xFFF);
  __syncthreads();

  // --- main loop: R10-verified gathered full-row stream ---
  const float4* __restrict__ Ab = (const float4*)(a + (size_t)b * SL * SL);
  float4 creg{0, 0, 0, 0};
  int pcur = -1;

  int    eA[8], eB[8];
  float4 vA[8], vB[8];
  auto loadbank = [&](int (&e)[8], float4 (&v)[8], int k) {
    #pragma unroll
    for (int u = 0; u < 8; ++u) {
      e[u] = __builtin_amdgcn_readfirstlane(list[k + u]);  // uniform -> SGPR
      v[u] = Ab[(size_t)(e[u] & 0xFFF) * (SL / 4) + tid];  // 1 KB/wave-instr
    }
  };
  auto flushcreg = [&]() {
    if (pcur >= 0 && pcur < 4)          // block-uniform; skips sentinel
      ((float4*)&accL[pcur][0])[tid] = creg;   // one plain store per p-run
  };
  auto procbank = [&](int (&e)[8], float4 (&v)[8]) {
    #pragma unroll
    for (int u = 0; u < 8; ++u) {
      const int pl = e[u] >> 12;
      if (pl != pcur) { flushcreg(); creg = float4{0, 0, 0, 0}; pcur = pl; }
      creg.x += v[u].x; creg.y += v[u].y; creg.z += v[u].z; creg.w += v[u].w;
    }
  };

  if (Npad > 0) {
    pcur = list[0] >> 12;
    loadbank(eA, vA, 0);
    for (int k = 0; k < Npad; k += 16) {
      if (k + 8 < Npad) loadbank(eB, vB, k + 8);
      procbank(eA, vA);
      if (k + 16 < Npad) loadbank(eA, vA, k + 16);
      if (k + 8 < Npad) procbank(eB, vB);
    }
    flushcreg();
  }
  __syncthreads();

  // --- one-time col flush: 16 LDS-atomic instrs (NOT per-element) ---
  {
    const int4 qv = ((const int4*)adds_s)[tid];   // this thread's 4 col bins
    for (int pl = 0; pl < sz; ++pl) {
      const float4 av = ((float4*)&accL[pl][0])[tid];
      atomicAdd(&sbin[pl * NPOS + qv.x], av.x);
      atomicAdd(&sbin[pl * NPOS + qv.y], av.y);
      atomicAdd(&sbin[pl * NPOS + qv.z], av.z);
      atomicAdd(&sbin[pl * NPOS + qv.w], av.w);
    }
  }
  __syncthreads();

  float* __restrict__ gp = g_part + (size_t)blockIdx.x * PSLICE;
  for (int k = tid; k < sz * NPOS; k += H_THREADS) gp[k] = sbin[k];
}

// ---------------------------------------------------------------------------
// Kernel 1.5: g_hist[bin] = sum over 64 batches x 3 thirds. One thread per
// bin, plain stores -> no atomics, no memset anywhere.
// ---------------------------------------------------------------------------
__global__ __launch_bounds__(256) void reduce2(
    const float* __restrict__ g_part, float* __restrict__ g_hist) {
  const int bin = blockIdx.x * 256 + threadIdx.x;
  if (bin >= NBINS) return;
  const int p = bin / NPOS, q = bin % NPOS;
  const int rg = p >> 2, pl = p & 3;
  const float* __restrict__ base =
      g_part + (size_t)(rg * NSPL) * PSLICE + pl * NPOS + q;
  float s = 0.0f;
  #pragma unroll 4
  for (int bb = 0; bb < BZ; ++bb) {
    const size_t o = (size_t)bb * (NRNG * NSPL) * PSLICE;
    s += base[o] + base[o + PSLICE] + base[o + 2 * PSLICE];
  }
  g_hist[bin] = s;
}

// ---------------------------------------------------------------------------
// Kernel 2: out = s_arc + ALPHA * sigmoid(g_hist)[pos-pair bin]
// Measured ~6.1 TB/s (HBM roofline) — unchanged.
// ---------------------------------------------------------------------------
__global__ __launch_bounds__(A_THREADS) void apply_kernel(
    const float* __restrict__ s, const int* __restrict__ pos,
    const float* __restrict__ g_hist, float* __restrict__ out) {
  __shared__ float sig[NBINS];
  __shared__ int   pos_s[SL];

  const int tid = threadIdx.x;
  const int b   = blockIdx.x / BLOCKS_PER_B;
  const int i0  = (blockIdx.x % BLOCKS_PER_B) * ROWS_PER_BLOCK;

  ((int4*)pos_s)[tid] = ((const int4*)(pos + (size_t)b * SL))[tid];
  for (int k = tid; k < NBINS; k += A_THREADS) {
    const float h = g_hist[k];
    sig[k] = 1.0f / (1.0f + __expf(-h));
  }
  __syncthreads();

  const int4 pj = ((const int4*)pos_s)[tid];
  const size_t rowoff = ((size_t)b * SL + i0) * SL;
  const float4* __restrict__ srow = (const float4*)(s + rowoff);
  float4* __restrict__ orow = (float4*)(out + rowoff);

  for (int r = 0; r < ROWS_PER_BLOCK; ++r) {
    const int base = pos_s[i0 + r] * NPOS;    // wave-uniform broadcast
    const float4 sv = srow[(size_t)r * (SL / 4) + tid];
    float4 ov;
    ov.x = sv.x + ALPHA * sig[base + pj.x];
    ov.y = sv.y + ALPHA * sig[base + pj.y];
    ov.z = sv.z + ALPHA * sig[base + pj.z];
    ov.w = sv.w + ALPHA * sig[base + pj.w];
    orow[(size_t)r * (SL / 4) + tid] = ov;
  }
}

extern "C" void kernel_launch(void* const* d_in, const int* in_sizes, int n_in,
                              void* d_out, int out_size, void* d_ws, size_t ws_size,
                              hipStream_t stream) {
  const float* a_arc = (const float*)d_in[0];
  const float* s_arc = (const float*)d_in[1];
  const int*   adds  = (const int*)d_in[2];
  const int*   pos   = (const int*)d_in[3];
  float* out    = (float*)d_out;
  float* g_hist = (float*)d_ws;                 // 2500 floats
  float* g_part = g_hist + 4096;                // 2496 x 208 floats = 2.1 MB

  // No memset needed: all outputs are fully overwritten with plain stores
  // every call (no global atomics anywhere).
  hist_gather <<<H_BLOCKS, H_THREADS, 0, stream>>>(a_arc, adds, g_part);
  reduce2     <<<R2_BLOCKS, 256, 0, stream>>>(g_part, g_hist);
  apply_kernel<<<A_BLOCKS, A_THREADS, 0, stream>>>(s_arc, pos, g_hist, out);
}

// Round 16
// 163.554 us; speedup vs baseline: 1.6260x; 1.2199x over previous
//
#include <hip/hip_runtime.h>

// Problem constants (fixed by setup_inputs):
//   a_arc, s_arc : [64, 1024, 1024] f32
//   adds, pos    : [64, 1024] int32 in [0, 50)
constexpr int NPOS  = 50;
constexpr int NBINS = NPOS * NPOS;   // 2500
constexpr int SL    = 1024;
constexpr int BZ    = 64;
constexpr float ALPHA = 0.3f;

using nat_f4 = __attribute__((ext_vector_type(4))) float;   // NT-loadable

// ---------------- hist (row-gather) config — R10 verbatim ----------------
constexpr int NRNG      = 8;
constexpr int PSLICE    = 352;                 // per-block output slice (floats)
constexpr int H_THREADS = 256;                 // thread t owns cols 4t..4t+3
constexpr int H_BLOCKS  = BZ * NRNG;           // 512

__device__ __forceinline__ int rng_lo(int r) { return r < 2 ? 7 * r : 14 + 6 * (r - 2); }
__device__ __forceinline__ int rng_sz(int r) { return r < 2 ? 7 : 6; }

// ---------------- reduce2 / apply config ----------------
constexpr int R2_THREADS = 256;
constexpr int R2_BLOCKS  = (NBINS + R2_THREADS - 1) / R2_THREADS;  // 10
constexpr int A_THREADS      = 256;
constexpr int ROWS_PER_BLOCK = 32;
constexpr int BLOCKS_PER_B   = SL / ROWS_PER_BLOCK;   // 32
constexpr int A_BLOCKS       = BZ * BLOCKS_PER_B;     // 2048

// ---------------------------------------------------------------------------
// Kernel 1: R10's verified gather hist (best: 180.5us total). SINGLE CHANGE:
// the A-row loads are NONTEMPORAL (via native ext_vector_type, which the
// builtin accepts) — probe of the ~3.0-3.15 TB/s demand-read ceiling seen
// across every kernel in rounds 0-13. If the cap is L3-allocation policy,
// NT lifts it; if it's a fabric read limit, dur is unchanged and R10 is the
// roofline.
// ---------------------------------------------------------------------------
__global__ __launch_bounds__(H_THREADS) void hist_gather(
    const float* __restrict__ a, const int* __restrict__ adds,
    float* __restrict__ g_part) {
  __shared__ int   adds_s[SL];          // 4 KB
  __shared__ float accL[8][SL];         // 32 KB: [p_loc][col]; slot 7 = dummy
  __shared__ int   list[SL + 8];        // 4 KB: (p_loc<<12)|row, sorted by p
  __shared__ int   order2[SL];          // 4 KB: cols sorted by q
  __shared__ int   cnt8[8], off8[8];
  __shared__ int   cntQ[NPOS], offQs[NPOS], offQm[NPOS];
  __shared__ int   nrows_s;

  const int tid = threadIdx.x;
  const int b   = blockIdx.x / NRNG;
  const int rg  = blockIdx.x % NRNG;
  const int lo  = rng_lo(rg), sz = rng_sz(rg);

  ((int4*)adds_s)[tid] = ((const int4*)(adds + (size_t)b * SL))[tid];
  #pragma unroll
  for (int p = 0; p < 8; ++p) ((float4*)&accL[p][0])[tid] = float4{0, 0, 0, 0};
  if (tid < 8) cnt8[tid] = 0;
  if (tid < NPOS) cntQ[tid] = 0;
  __syncthreads();

  // --- counting sorts: range-rows by p_loc, all cols by q (verified) ---
  for (int i = tid; i < SL; i += H_THREADS) {
    const int p = adds_s[i];
    const int pl = p - lo;
    if ((unsigned)pl < (unsigned)sz) atomicAdd(&cnt8[pl], 1);
    atomicAdd(&cntQ[p], 1);
  }
  __syncthreads();
  if (tid == 0) {                       // wave 0: row prefix
    int run = 0;
    #pragma unroll
    for (int c = 0; c < 8; ++c) { off8[c] = run; run += cnt8[c]; }
    nrows_s = run;
  } else if (tid == 64) {               // wave 1: col prefix, concurrent
    int run = 0;
    for (int c = 0; c < NPOS; ++c) { offQs[c] = run; offQm[c] = run; run += cntQ[c]; }
  }
  __syncthreads();
  for (int i = tid; i < SL; i += H_THREADS) {
    const int p = adds_s[i];
    const int pl = p - lo;
    if ((unsigned)pl < (unsigned)sz)
      list[atomicAdd(&off8[pl], 1)] = (pl << 12) | i;
    order2[atomicAdd(&offQm[p], 1)] = i;
  }
  __syncthreads();
  const int N    = nrows_s;
  const int Npad = (N + 7) & ~7;
  if (tid < 8 && N + tid < Npad)        // pad: sentinel p_loc=7, valid row
    list[N + tid] = (7 << 12) | (N > 0 ? (list[N - 1] & 0xFFF) : 0);
  __syncthreads();

  // --- main loop: stream sorted rows, 8-deep ping-pong, 4-KB-granular ---
  const nat_f4* __restrict__ Ab = (const nat_f4*)(a + (size_t)b * SL * SL);
  float4 creg = {0, 0, 0, 0};
  int pcur = 7;

  int    eA[8], eB[8];
  nat_f4 vA[8], vB[8];
  auto loadbank = [&](int (&e)[8], nat_f4 (&v)[8], int k) {
    #pragma unroll
    for (int u = 0; u < 8; ++u) {
      e[u] = __builtin_amdgcn_readfirstlane(list[k + u]);  // uniform -> SGPR
      v[u] = __builtin_nontemporal_load(
          Ab + (size_t)(e[u] & 0xFFF) * (SL / 4) + tid);   // NT 1 KB/wave-instr
    }
  };
  auto procbank = [&](int (&e)[8], nat_f4 (&v)[8]) {
    #pragma unroll
    for (int u = 0; u < 8; ++u) {
      const int pl = e[u] >> 12;
      if (pl != pcur) {                 // block-uniform scalar branch
        ((float4*)&accL[pcur][0])[tid] = creg;   // one store per p-run
        creg = float4{0, 0, 0, 0};
        pcur = pl;
      }
      creg.x += v[u][0]; creg.y += v[u][1]; creg.z += v[u][2]; creg.w += v[u][3];
    }
  };

  if (Npad > 0) {
    pcur = list[0] >> 12;
    loadbank(eA, vA, 0);
    for (int k = 0; k < Npad; k += 16) {
      if (k + 8 < Npad) loadbank(eB, vB, k + 8);
      procbank(eA, vA);
      if (k + 16 < Npad) loadbank(eA, vA, k + 16);
      if (k + 8 < Npad) procbank(eB, vB);
    }
    ((float4*)&accL[pcur][0])[tid] = creg;       // final flush (7 = dummy ok)
  }
  __syncthreads();

  // --- col reduce: slice[pl*50+q] = sum_{cols j: adds[j]==q} accL[pl][j] ---
  float* __restrict__ gp = g_part + (size_t)blockIdx.x * PSLICE;
  for (int bin = tid; bin < sz * NPOS; bin += H_THREADS) {
    const int pl = bin / NPOS, q = bin % NPOS;
    const int s0 = offQs[q], n = cntQ[q];
    float s = 0.0f;
    for (int k2 = 0; k2 < n; ++k2) s += accL[pl][order2[s0 + k2]];
    gp[bin] = s;                        // plain store, private slice
  }
}

// ---------------------------------------------------------------------------
// Kernel 1.5: g_hist[bin] = sum over 64 batches of that bin's range-slice.
// Plain stores; each bin owned by one thread -> no atomics, no memset.
// ---------------------------------------------------------------------------
__global__ __launch_bounds__(R2_THREADS) void reduce2(
    const float* __restrict__ g_part, float* __restrict__ g_hist) {
  const int bin = blockIdx.x * R2_THREADS + threadIdx.x;
  if (bin >= NBINS) return;
  const int p = bin / NPOS, q = bin % NPOS;
  const int rg = (p < 14) ? p / 7 : 2 + (p - 14) / 6;
  const int pl = (p < 14) ? p % 7 : (p - 14) % 6;
  float s = 0.0f;
  #pragma unroll 8
  for (int bb = 0; bb < BZ; ++bb)
    s += g_part[(size_t)(bb * NRNG + rg) * PSLICE + pl * NPOS + q];
  g_hist[bin] = s;
}

// ---------------------------------------------------------------------------
// Kernel 2: out = s_arc + ALPHA * sigmoid(g_hist)[pos-pair bin]
// Read-side at the ~3.05 TB/s ceiling — unchanged.
// ---------------------------------------------------------------------------
__global__ __launch_bounds__(A_THREADS) void apply_kernel(
    const float* __restrict__ s, const int* __restrict__ pos,
    const float* __restrict__ g_hist, float* __restrict__ out) {
  __shared__ float sig[NBINS];
  __shared__ int   pos_s[SL];

  const int tid = threadIdx.x;
  const int b   = blockIdx.x / BLOCKS_PER_B;
  const int i0  = (blockIdx.x % BLOCKS_PER_B) * ROWS_PER_BLOCK;

  ((int4*)pos_s)[tid] = ((const int4*)(pos + (size_t)b * SL))[tid];
  for (int k = tid; k < NBINS; k += A_THREADS) {
    const float h = g_hist[k];
    sig[k] = 1.0f / (1.0f + __expf(-h));
  }
  __syncthreads();

  const int4 pj = ((const int4*)pos_s)[tid];
  const size_t rowoff = ((size_t)b * SL + i0) * SL;
  const float4* __restrict__ srow = (const float4*)(s + rowoff);
  float4* __restrict__ orow = (float4*)(out + rowoff);

  for (int r = 0; r < ROWS_PER_BLOCK; ++r) {
    const int base = pos_s[i0 + r] * NPOS;    // wave-uniform broadcast
    const float4 sv = srow[(size_t)r * (SL / 4) + tid];
    float4 ov;
    ov.x = sv.x + ALPHA * sig[base + pj.x];
    ov.y = sv.y + ALPHA * sig[base + pj.y];
    ov.z = sv.z + ALPHA * sig[base + pj.z];
    ov.w = sv.w + ALPHA * sig[base + pj.w];
    orow[(size_t)r * (SL / 4) + tid] = ov;
  }
}

extern "C" void kernel_launch(void* const* d_in, const int* in_sizes, int n_in,
                              void* d_out, int out_size, void* d_ws, size_t ws_size,
                              hipStream_t stream) {
  const float* a_arc = (const float*)d_in[0];
  const float* s_arc = (const float*)d_in[1];
  const int*   adds  = (const int*)d_in[2];
  const int*   pos   = (const int*)d_in[3];
  float* out    = (float*)d_out;
  float* g_hist = (float*)d_ws;                 // 2500 floats
  float* g_part = g_hist + 4096;                // 512 x 352 floats = 0.72 MB

  // No memset needed: g_part slices and g_hist are fully overwritten with
  // plain stores every call (no atomic accumulation anywhere).
  hist_gather <<<H_BLOCKS, H_THREADS, 0, stream>>>(a_arc, adds, g_part);
  reduce2     <<<R2_BLOCKS, R2_THREADS, 0, stream>>>(g_part, g_hist);
  apply_kernel<<<A_BLOCKS, A_THREADS, 0, stream>>>(s_arc, pos, g_hist, out);
}

// Round 17
// 156.331 us; speedup vs baseline: 1.7012x; 1.0462x over previous
//
#include <hip/hip_runtime.h>

// Problem constants (fixed by setup_inputs):
//   a_arc, s_arc : [64, 1024, 1024] f32
//   adds, pos    : [64, 1024] int32 in [0, 50)
constexpr int NPOS  = 50;
constexpr int NBINS = NPOS * NPOS;   // 2500
constexpr int SL    = 1024;
constexpr int BZ    = 64;
constexpr float ALPHA = 0.3f;

using nat_f4 = __attribute__((ext_vector_type(4))) float;   // NT-loadable

// ---------------- hist (row-gather) config — R15 verbatim ----------------
constexpr int NRNG      = 8;
constexpr int PSLICE    = 352;                 // per-block output slice (floats)
constexpr int H_THREADS = 256;                 // thread t owns cols 4t..4t+3
constexpr int H_BLOCKS  = BZ * NRNG;           // 512

__device__ __forceinline__ int rng_lo(int r) { return r < 2 ? 7 * r : 14 + 6 * (r - 2); }
__device__ __forceinline__ int rng_sz(int r) { return r < 2 ? 7 : 6; }

// ---------------- reduce2 / apply config ----------------
constexpr int R2_THREADS = 256;
constexpr int R2_BLOCKS  = (NBINS + R2_THREADS - 1) / R2_THREADS;  // 10
constexpr int A_THREADS      = 256;
constexpr int ROWS_PER_BLOCK = 32;
constexpr int BLOCKS_PER_B   = SL / ROWS_PER_BLOCK;   // 32
constexpr int A_BLOCKS       = BZ * BLOCKS_PER_B;     // 2048

// ---------------------------------------------------------------------------
// Kernel 1: R15's verified NT-load gather hist (163.6us total) — unchanged.
// NT loads lifted the demand-read rate ~20% (L3-allocation artifact, R15).
// ---------------------------------------------------------------------------
__global__ __launch_bounds__(H_THREADS) void hist_gather(
    const float* __restrict__ a, const int* __restrict__ adds,
    float* __restrict__ g_part) {
  __shared__ int   adds_s[SL];          // 4 KB
  __shared__ float accL[8][SL];         // 32 KB: [p_loc][col]; slot 7 = dummy
  __shared__ int   list[SL + 8];        // 4 KB: (p_loc<<12)|row, sorted by p
  __shared__ int   order2[SL];          // 4 KB: cols sorted by q
  __shared__ int   cnt8[8], off8[8];
  __shared__ int   cntQ[NPOS], offQs[NPOS], offQm[NPOS];
  __shared__ int   nrows_s;

  const int tid = threadIdx.x;
  const int b   = blockIdx.x / NRNG;
  const int rg  = blockIdx.x % NRNG;
  const int lo  = rng_lo(rg), sz = rng_sz(rg);

  ((int4*)adds_s)[tid] = ((const int4*)(adds + (size_t)b * SL))[tid];
  #pragma unroll
  for (int p = 0; p < 8; ++p) ((float4*)&accL[p][0])[tid] = float4{0, 0, 0, 0};
  if (tid < 8) cnt8[tid] = 0;
  if (tid < NPOS) cntQ[tid] = 0;
  __syncthreads();

  // --- counting sorts: range-rows by p_loc, all cols by q (verified) ---
  for (int i = tid; i < SL; i += H_THREADS) {
    const int p = adds_s[i];
    const int pl = p - lo;
    if ((unsigned)pl < (unsigned)sz) atomicAdd(&cnt8[pl], 1);
    atomicAdd(&cntQ[p], 1);
  }
  __syncthreads();
  if (tid == 0) {                       // wave 0: row prefix
    int run = 0;
    #pragma unroll
    for (int c = 0; c < 8; ++c) { off8[c] = run; run += cnt8[c]; }
    nrows_s = run;
  } else if (tid == 64) {               // wave 1: col prefix, concurrent
    int run = 0;
    for (int c = 0; c < NPOS; ++c) { offQs[c] = run; offQm[c] = run; run += cntQ[c]; }
  }
  __syncthreads();
  for (int i = tid; i < SL; i += H_THREADS) {
    const int p = adds_s[i];
    const int pl = p - lo;
    if ((unsigned)pl < (unsigned)sz)
      list[atomicAdd(&off8[pl], 1)] = (pl << 12) | i;
    order2[atomicAdd(&offQm[p], 1)] = i;
  }
  __syncthreads();
  const int N    = nrows_s;
  const int Npad = (N + 7) & ~7;
  if (tid < 8 && N + tid < Npad)        // pad: sentinel p_loc=7, valid row
    list[N + tid] = (7 << 12) | (N > 0 ? (list[N - 1] & 0xFFF) : 0);
  __syncthreads();

  // --- main loop: stream sorted rows, 8-deep ping-pong, 4-KB-granular ---
  const nat_f4* __restrict__ Ab = (const nat_f4*)(a + (size_t)b * SL * SL);
  float4 creg = {0, 0, 0, 0};
  int pcur = 7;

  int    eA[8], eB[8];
  nat_f4 vA[8], vB[8];
  auto loadbank = [&](int (&e)[8], nat_f4 (&v)[8], int k) {
    #pragma unroll
    for (int u = 0; u < 8; ++u) {
      e[u] = __builtin_amdgcn_readfirstlane(list[k + u]);  // uniform -> SGPR
      v[u] = __builtin_nontemporal_load(
          Ab + (size_t)(e[u] & 0xFFF) * (SL / 4) + tid);   // NT 1 KB/wave-instr
    }
  };
  auto procbank = [&](int (&e)[8], nat_f4 (&v)[8]) {
    #pragma unroll
    for (int u = 0; u < 8; ++u) {
      const int pl = e[u] >> 12;
      if (pl != pcur) {                 // block-uniform scalar branch
        ((float4*)&accL[pcur][0])[tid] = creg;   // one store per p-run
        creg = float4{0, 0, 0, 0};
        pcur = pl;
      }
      creg.x += v[u][0]; creg.y += v[u][1]; creg.z += v[u][2]; creg.w += v[u][3];
    }
  };

  if (Npad > 0) {
    pcur = list[0] >> 12;
    loadbank(eA, vA, 0);
    for (int k = 0; k < Npad; k += 16) {
      if (k + 8 < Npad) loadbank(eB, vB, k + 8);
      procbank(eA, vA);
      if (k + 16 < Npad) loadbank(eA, vA, k + 16);
      if (k + 8 < Npad) procbank(eB, vB);
    }
    ((float4*)&accL[pcur][0])[tid] = creg;       // final flush (7 = dummy ok)
  }
  __syncthreads();

  // --- col reduce: slice[pl*50+q] = sum_{cols j: adds[j]==q} accL[pl][j] ---
  float* __restrict__ gp = g_part + (size_t)blockIdx.x * PSLICE;
  for (int bin = tid; bin < sz * NPOS; bin += H_THREADS) {
    const int pl = bin / NPOS, q = bin % NPOS;
    const int s0 = offQs[q], n = cntQ[q];
    float s = 0.0f;
    for (int k2 = 0; k2 < n; ++k2) s += accL[pl][order2[s0 + k2]];
    gp[bin] = s;                        // plain store, private slice
  }
}

// ---------------------------------------------------------------------------
// Kernel 1.5: g_hist[bin] = sum over 64 batches of that bin's range-slice.
// ---------------------------------------------------------------------------
__global__ __launch_bounds__(R2_THREADS) void reduce2(
    const float* __restrict__ g_part, float* __restrict__ g_hist) {
  const int bin = blockIdx.x * R2_THREADS + threadIdx.x;
  if (bin >= NBINS) return;
  const int p = bin / NPOS, q = bin % NPOS;
  const int rg = (p < 14) ? p / 7 : 2 + (p - 14) / 6;
  const int pl = (p < 14) ? p % 7 : (p - 14) % 6;
  float s = 0.0f;
  #pragma unroll 8
  for (int bb = 0; bb < BZ; ++bb)
    s += g_part[(size_t)(bb * NRNG + rg) * PSLICE + pl * NPOS + q];
  g_hist[bin] = s;
}

// ---------------------------------------------------------------------------
// Kernel 2: out = s_arc + ALPHA * sigmoid(g_hist)[pos-pair bin].
// NEW vs R15: NT load of s_arc (stream-once) + NT store of out (never
// re-read on-device) — same L3-allocation-bypass mechanism that won R15.
// ---------------------------------------------------------------------------
__global__ __launch_bounds__(A_THREADS) void apply_kernel(
    const float* __restrict__ s, const int* __restrict__ pos,
    const float* __restrict__ g_hist, float* __restrict__ out) {
  __shared__ float sig[NBINS];
  __shared__ int   pos_s[SL];

  const int tid = threadIdx.x;
  const int b   = blockIdx.x / BLOCKS_PER_B;
  const int i0  = (blockIdx.x % BLOCKS_PER_B) * ROWS_PER_BLOCK;

  ((int4*)pos_s)[tid] = ((const int4*)(pos + (size_t)b * SL))[tid];
  for (int k = tid; k < NBINS; k += A_THREADS) {
    const float h = g_hist[k];
    sig[k] = 1.0f / (1.0f + __expf(-h));
  }
  __syncthreads();

  const int4 pj = ((const int4*)pos_s)[tid];
  const size_t rowoff = ((size_t)b * SL + i0) * SL;
  const nat_f4* __restrict__ srow = (const nat_f4*)(s + rowoff);
  nat_f4* __restrict__ orow = (nat_f4*)(out + rowoff);

  for (int r = 0; r < ROWS_PER_BLOCK; ++r) {
    const int base = pos_s[i0 + r] * NPOS;    // wave-uniform broadcast
    const nat_f4 sv =
        __builtin_nontemporal_load(srow + (size_t)r * (SL / 4) + tid);
    nat_f4 ov;
    ov[0] = sv[0] + ALPHA * sig[base + pj.x];
    ov[1] = sv[1] + ALPHA * sig[base + pj.y];
    ov[2] = sv[2] + ALPHA * sig[base + pj.z];
    ov[3] = sv[3] + ALPHA * sig[base + pj.w];
    __builtin_nontemporal_store(ov, orow + (size_t)r * (SL / 4) + tid);
  }
}

extern "C" void kernel_launch(void* const* d_in, const int* in_sizes, int n_in,
                              void* d_out, int out_size, void* d_ws, size_t ws_size,
                              hipStream_t stream) {
  const float* a_arc = (const float*)d_in[0];
  const float* s_arc = (const float*)d_in[1];
  const int*   adds  = (const int*)d_in[2];
  const int*   pos   = (const int*)d_in[3];
  float* out    = (float*)d_out;
  float* g_hist = (float*)d_ws;                 // 2500 floats
  float* g_part = g_hist + 4096;                // 512 x 352 floats = 0.72 MB

  // No memset needed: g_part slices and g_hist are fully overwritten with
  // plain stores every call (no atomic accumulation anywhere).
  hist_gather <<<H_BLOCKS, H_THREADS, 0, stream>>>(a_arc, adds, g_part);
  reduce2     <<<R2_BLOCKS, R2_THREADS, 0, stream>>>(g_part, g_hist);
  apply_kernel<<<A_BLOCKS, A_THREADS, 0, stream>>>(s_arc, pos, g_hist, out);
}